// Round 2
// baseline (133.349 us; speedup 1.0000x reference)
//
#include <hip/hip_runtime.h>
#include <hip/hip_bf16.h>

// Problem constants: B=2, T=2048, D=1024, H=16, DK=64
// Math reduction: y = permute(x @ Wv) @ Wo^T  (softmax rowsum == 1 exactly;
// reference's einsum 'bhtl,bthd->bhtd' never contracts v with A over l, so
// o[b,h,t,:] = (sum_l A[b,h,t,l]) * v[b,t,h,:] = v[b,t,h,:]).
// Permute: V[b*2048+t][h*64+k] -> Vp[b*2048 + h*128 + t/16][(t%16)*64 + k]
// Inputs/outputs are FP32 (reference dtype). Internal compute bf16 MFMA,
// fp32 accumulate; threshold is 2% of max|ref| so bf16 rounding is fine.

using bf16 = __hip_bfloat16;
typedef __attribute__((ext_vector_type(8))) short bf16x8;   // 8 bf16 = 4 VGPRs
typedef __attribute__((ext_vector_type(4))) float f32x4;

__device__ __forceinline__ void gld_lds16(const void* g, void* l) {
    // async global->LDS, 16B/lane; LDS dest = wave-uniform base + lane*16
    __builtin_amdgcn_global_load_lds(
        (const __attribute__((address_space(1))) void*)g,
        (__attribute__((address_space(3))) void*)l, 16, 0, 0);
}

// ---------------- fp32 -> bf16 convert (n multiple of 4) -------------------
__global__ __launch_bounds__(256) void cvt_f32_bf16(const float* __restrict__ in,
                                                    bf16* __restrict__ out, int n4) {
    int i = blockIdx.x * 256 + threadIdx.x;
    if (i >= n4) return;
    const float4 v = ((const float4*)in)[i];
    bf16 o[4] = {__float2bfloat16(v.x), __float2bfloat16(v.y),
                 __float2bfloat16(v.z), __float2bfloat16(v.w)};
    ((ulong1*)out)[i] = *(ulong1*)o;   // 8B store
}

// -------- Wv transpose+convert: out[n][k] = bf16(in[k][n]), 1024x1024 ------
__global__ __launch_bounds__(256) void transpose1024(const float* __restrict__ in,
                                                     bf16* __restrict__ out) {
    __shared__ float tile[64][65];
    const int bx = blockIdx.x, by = blockIdx.y;
    const int t = threadIdx.x;
    const int c = t & 63, r4 = t >> 6;      // 64 cols, 4 rows/phase
#pragma unroll
    for (int p = 0; p < 16; ++p) {
        int r = p * 4 + r4;
        tile[r][c] = in[(size_t)(by * 64 + r) * 1024 + bx * 64 + c];
    }
    __syncthreads();
#pragma unroll
    for (int p = 0; p < 16; ++p) {
        int r = p * 4 + r4;
        out[(size_t)(bx * 64 + r) * 1024 + by * 64 + c] = __float2bfloat16(tile[c][r]);
    }
}

// ---------------- GEMM  C = A(Mx1024) * Bt(1024x1024)^T --------------------
// A, Bt bf16 row-major [.][K]: both operands K-contiguous.
// 128x128 tile / 256 threads (4 waves, each 64x64 = 4x4 MFMA 16x16x32 accs).
__device__ __forceinline__ void storeC(float v, bf16* p)  { *p = __float2bfloat16(v); }
__device__ __forceinline__ void storeC(float v, float* p) { *p = v; }

template <bool PERMUTE, typename OutT>
__global__ __launch_bounds__(256) void gemm_bt(const bf16* __restrict__ A,
                                               const bf16* __restrict__ Bt,
                                               OutT* __restrict__ C) {
    __shared__ __align__(16) bf16 sA[128 * 32];   // 8 KB
    __shared__ __align__(16) bf16 sB[128 * 32];   // 8 KB

    const int tid  = threadIdx.x;
    const int wave = tid >> 6;
    const int lane = tid & 63;
    const int m0 = blockIdx.x * 128;
    const int n0 = blockIdx.y * 128;

    // wave -> 64x64 quadrant of the 128x128 tile
    const int wr = (wave >> 1) * 64;
    const int wc = (wave & 1) * 64;

    // staging: thread t loads 8 bf16 (16B) from row (t>>2), col (t&3)*8;
    // LDS element offset = wave*512 + lane*8 == row*32 + col  (verified identity)
    const int srow = tid >> 2;            // 0..63
    const int scol = (tid & 3) * 8;
    const bf16* gA = A  + (size_t)(m0 + srow) * 1024 + scol;
    const bf16* gB = Bt + (size_t)(n0 + srow) * 1024 + scol;
    bf16* sA0 = sA + wave * 512;          // rows 0..63
    bf16* sA1 = sA + 2048 + wave * 512;   // rows 64..127
    bf16* sB0 = sB + wave * 512;
    bf16* sB1 = sB + 2048 + wave * 512;

    f32x4 acc[4][4];
#pragma unroll
    for (int i = 0; i < 4; ++i)
#pragma unroll
        for (int j = 0; j < 4; ++j)
            acc[i][j] = (f32x4){0.f, 0.f, 0.f, 0.f};

    const int fr = lane & 15;             // fragment row (A) / col (B)
    const int q8 = (lane >> 4) * 8;       // k offset within BK=32

    for (int kt = 0; kt < 1024; kt += 32) {
        __syncthreads();                  // prior ds_reads done before overwrite
        gld_lds16(gA + kt,               sA0);
        gld_lds16(gA + kt + 64 * 1024,   sA1);
        gld_lds16(gB + kt,               sB0);
        gld_lds16(gB + kt + 64 * 1024,   sB1);
        __syncthreads();                  // drains vmcnt -> LDS visible

        bf16x8 aF[4], bF[4];
#pragma unroll
        for (int i = 0; i < 4; ++i)
            aF[i] = *(const bf16x8*)&sA[(wr + i * 16 + fr) * 32 + q8];
#pragma unroll
        for (int j = 0; j < 4; ++j)
            bF[j] = *(const bf16x8*)&sB[(wc + j * 16 + fr) * 32 + q8];
#pragma unroll
        for (int i = 0; i < 4; ++i)
#pragma unroll
            for (int j = 0; j < 4; ++j)
                acc[i][j] = __builtin_amdgcn_mfma_f32_16x16x32_bf16(
                    aF[i], bF[j], acc[i][j], 0, 0, 0);
    }

    // epilogue: C/D layout col=lane&15, row=(lane>>4)*4+reg  [m91-verified]
#pragma unroll
    for (int i = 0; i < 4; ++i) {
#pragma unroll
        for (int j = 0; j < 4; ++j) {
            const int col = n0 + wc + j * 16 + (lane & 15);
#pragma unroll
            for (int r = 0; r < 4; ++r) {
                const int row = m0 + wr + i * 16 + (lane >> 4) * 4 + r;
                if (PERMUTE) {
                    const int b = row >> 11, t = row & 2047;
                    const int h = col >> 6,  k = col & 63;
                    const int rr = (b << 11) | (h << 7) | (t >> 4);
                    const int cc = ((t & 15) << 6) | k;
                    storeC(acc[i][j][r], &C[(size_t)rr * 1024 + cc]);
                } else {
                    storeC(acc[i][j][r], &C[(size_t)row * 1024 + col]);
                }
            }
        }
    }
}

extern "C" void kernel_launch(void* const* d_in, const int* in_sizes, int n_in,
                              void* d_out, int out_size, void* d_ws, size_t ws_size,
                              hipStream_t stream) {
    (void)in_sizes; (void)n_in; (void)out_size; (void)ws_size;
    // inputs (fp32): x, mask, Wq, Wk, Wv, Wo  (mask/Wq/Wk dead — see header)
    const float* x  = (const float*)d_in[0];
    const float* Wv = (const float*)d_in[4];
    const float* Wo = (const float*)d_in[5];
    float* out = (float*)d_out;

    bf16* xb    = (bf16*)d_ws;                 // 4096*1024 bf16 = 8 MB
    bf16* WvT   = xb    + 4096 * 1024;         // 2 MB
    bf16* Wob   = WvT   + 1024 * 1024;         // 2 MB
    bf16* vperm = Wob   + 1024 * 1024;         // 8 MB   (total 20 MB)

    // fp32 -> bf16 conversions
    cvt_f32_bf16<<<4096, 256, 0, stream>>>(x,  xb,  4096 * 1024 / 4);
    cvt_f32_bf16<<<1024, 256, 0, stream>>>(Wo, Wob, 1024 * 1024 / 4);
    transpose1024<<<dim3(16, 16), 256, 0, stream>>>(Wv, WvT);   // WvT[n][k]=Wv[k][n]

    // V = x @ Wv, written permuted (bf16)
    gemm_bt<true,  bf16 ><<<dim3(32, 8), 256, 0, stream>>>(xb, WvT, vperm);
    // y = Vp @ Wo^T  (fp32 output)
    gemm_bt<false, float><<<dim3(32, 8), 256, 0, stream>>>(vperm, Wob, out);
}

// Round 3
// 120.476 us; speedup vs baseline: 1.1068x; 1.1068x over previous
//
#include <hip/hip_runtime.h>
#include <hip/hip_bf16.h>

// Problem constants: B=2, T=2048, D=1024, H=16, DK=64
// Math reduction: y = permute(x @ Wv) @ Wo^T  (softmax rowsum == 1 exactly;
// reference's einsum 'bhtl,bthd->bhtd' never contracts v with A over l, so
// o[b,h,t,:] = (sum_l A[b,h,t,l]) * v[b,t,h,:] = v[b,t,h,:]).
// Permute: V[b*2048+t][h*64+k] -> Vp[b*2048 + h*128 + t/16][(t%16)*64 + k]
// Inputs/outputs FP32 (reference dtype); internal bf16 MFMA, fp32 accum.
// R2: 128x64 GEMM tiles -> 512 blocks = 2 blocks/CU (was 256 = 1/CU, whole-CU
// barrier-drain stalls); prep fused into one dispatch.

using bf16 = __hip_bfloat16;
typedef __attribute__((ext_vector_type(8))) short bf16x8;   // 8 bf16 = 4 VGPRs
typedef __attribute__((ext_vector_type(4))) float f32x4;

__device__ __forceinline__ void gld_lds16(const void* g, void* l) {
    // async global->LDS, 16B/lane; LDS dest = wave-uniform base + lane*16
    __builtin_amdgcn_global_load_lds(
        (const __attribute__((address_space(1))) void*)g,
        (__attribute__((address_space(3))) void*)l, 16, 0, 0);
}

// ---- fused prep: Wv transpose+cvt | x cvt | Wo cvt, one dispatch ----------
// grid: [0,256)   -> transpose tile (id&15, id>>4)
//       [256,4352)-> cvt x   (float4 id - 256)
//       [4352,5376)-> cvt Wo (float4 id - 4352)
__global__ __launch_bounds__(256) void prep(const float* __restrict__ x,
                                            const float* __restrict__ Wv,
                                            const float* __restrict__ Wo,
                                            bf16* __restrict__ xb,
                                            bf16* __restrict__ WvT,
                                            bf16* __restrict__ Wob) {
    __shared__ float tile[64][65];
    const int id = blockIdx.x;
    const int t  = threadIdx.x;
    if (id < 256) {                       // Wv transpose+convert (64x64 tile)
        const int bx = id & 15, by = id >> 4;
        const int c = t & 63, r4 = t >> 6;
#pragma unroll
        for (int p = 0; p < 16; ++p) {
            int r = p * 4 + r4;
            tile[r][c] = Wv[(size_t)(by * 64 + r) * 1024 + bx * 64 + c];
        }
        __syncthreads();
#pragma unroll
        for (int p = 0; p < 16; ++p) {
            int r = p * 4 + r4;
            WvT[(size_t)(bx * 64 + r) * 1024 + by * 64 + c] = __float2bfloat16(tile[c][r]);
        }
    } else if (id < 4352) {               // x -> bf16, float4 per thread
        const int i = (id - 256) * 256 + t;
        const float4 v = ((const float4*)x)[i];
        bf16 o[4] = {__float2bfloat16(v.x), __float2bfloat16(v.y),
                     __float2bfloat16(v.z), __float2bfloat16(v.w)};
        ((ulong1*)xb)[i] = *(ulong1*)o;
    } else {                              // Wo -> bf16
        const int i = (id - 4352) * 256 + t;
        const float4 v = ((const float4*)Wo)[i];
        bf16 o[4] = {__float2bfloat16(v.x), __float2bfloat16(v.y),
                     __float2bfloat16(v.z), __float2bfloat16(v.w)};
        ((ulong1*)Wob)[i] = *(ulong1*)o;
    }
}

// ---------------- GEMM  C = A(Mx1024) * Bt(Nx1024)^T -----------------------
// A, Bt bf16 row-major [.][K]: both operands K-contiguous.
// 128x64 tile / 256 threads; 4 waves in 2x2, each wave 64x32 = 4x2 accs.
__device__ __forceinline__ void storeC(float v, bf16* p)  { *p = __float2bfloat16(v); }
__device__ __forceinline__ void storeC(float v, float* p) { *p = v; }

template <bool PERMUTE, typename OutT>
__global__ __launch_bounds__(256) void gemm_bt(const bf16* __restrict__ A,
                                               const bf16* __restrict__ Bt,
                                               OutT* __restrict__ C) {
    __shared__ __align__(16) bf16 sA[128 * 32];   // 8 KB
    __shared__ __align__(16) bf16 sB[64 * 32];    // 4 KB

    const int tid  = threadIdx.x;
    const int wave = tid >> 6;
    const int lane = tid & 63;
    const int m0 = blockIdx.x * 128;
    const int n0 = blockIdx.y * 64;

    // wave -> 64x32 quadrant of the 128x64 tile
    const int wr = (wave >> 1) * 64;
    const int wc = (wave & 1) * 32;

    // staging: thread t covers row tid>>2 (0..63), col (tid&3)*8;
    // LDS elem offset = row*32+col = tid*8 (matches lane*16B DMA order)
    const int srow = tid >> 2;
    const int scol = (tid & 3) * 8;
    const bf16* gA = A  + (size_t)(m0 + srow) * 1024 + scol;
    const bf16* gB = Bt + (size_t)(n0 + srow) * 1024 + scol;
    bf16* sA0 = sA + wave * 512;          // A rows 0..63
    bf16* sA1 = sA + 2048 + wave * 512;   // A rows 64..127
    bf16* sB0 = sB + wave * 512;          // B rows 0..63

    f32x4 acc[4][2];
#pragma unroll
    for (int i = 0; i < 4; ++i)
#pragma unroll
        for (int j = 0; j < 2; ++j)
            acc[i][j] = (f32x4){0.f, 0.f, 0.f, 0.f};

    const int fr = lane & 15;             // fragment row (A) / col (B)
    const int q8 = (lane >> 4) * 8;       // k offset within BK=32

    for (int kt = 0; kt < 1024; kt += 32) {
        __syncthreads();                  // prior ds_reads done before overwrite
        gld_lds16(gA + kt,             sA0);
        gld_lds16(gA + kt + 64 * 1024, sA1);
        gld_lds16(gB + kt,             sB0);
        __syncthreads();                  // drains vmcnt -> LDS visible

        bf16x8 aF[4], bF[2];
#pragma unroll
        for (int i = 0; i < 4; ++i)
            aF[i] = *(const bf16x8*)&sA[(wr + i * 16 + fr) * 32 + q8];
#pragma unroll
        for (int j = 0; j < 2; ++j)
            bF[j] = *(const bf16x8*)&sB[(wc + j * 16 + fr) * 32 + q8];
#pragma unroll
        for (int i = 0; i < 4; ++i)
#pragma unroll
            for (int j = 0; j < 2; ++j)
                acc[i][j] = __builtin_amdgcn_mfma_f32_16x16x32_bf16(
                    aF[i], bF[j], acc[i][j], 0, 0, 0);
    }

    // epilogue: C/D layout col=lane&15, row=(lane>>4)*4+reg  [m91-verified]
#pragma unroll
    for (int i = 0; i < 4; ++i) {
#pragma unroll
        for (int j = 0; j < 2; ++j) {
            const int col = n0 + wc + j * 16 + (lane & 15);
#pragma unroll
            for (int r = 0; r < 4; ++r) {
                const int row = m0 + wr + i * 16 + (lane >> 4) * 4 + r;
                if (PERMUTE) {
                    const int b = row >> 11, t = row & 2047;
                    const int h = col >> 6,  k = col & 63;
                    const int rr = (b << 11) | (h << 7) | (t >> 4);
                    const int cc = ((t & 15) << 6) | k;
                    storeC(acc[i][j][r], &C[(size_t)rr * 1024 + cc]);
                } else {
                    storeC(acc[i][j][r], &C[(size_t)row * 1024 + col]);
                }
            }
        }
    }
}

extern "C" void kernel_launch(void* const* d_in, const int* in_sizes, int n_in,
                              void* d_out, int out_size, void* d_ws, size_t ws_size,
                              hipStream_t stream) {
    (void)in_sizes; (void)n_in; (void)out_size; (void)ws_size;
    // inputs (fp32): x, mask, Wq, Wk, Wv, Wo  (mask/Wq/Wk dead — see header)
    const float* x  = (const float*)d_in[0];
    const float* Wv = (const float*)d_in[4];
    const float* Wo = (const float*)d_in[5];
    float* out = (float*)d_out;

    bf16* xb    = (bf16*)d_ws;                 // 4096*1024 bf16 = 8 MB
    bf16* WvT   = xb    + 4096 * 1024;         // 2 MB
    bf16* Wob   = WvT   + 1024 * 1024;         // 2 MB
    bf16* vperm = Wob   + 1024 * 1024;         // 8 MB   (total 20 MB)

    prep<<<5376, 256, 0, stream>>>(x, Wv, Wo, xb, WvT, Wob);
    // V = x @ Wv, written permuted (bf16)
    gemm_bt<true,  bf16 ><<<dim3(32, 16), 256, 0, stream>>>(xb, WvT, vperm);
    // y = Vp @ Wo^T  (fp32 output)
    gemm_bt<false, float><<<dim3(32, 16), 256, 0, stream>>>(vperm, Wob, out);
}

// Round 4
// 117.885 us; speedup vs baseline: 1.1312x; 1.0220x over previous
//
#include <hip/hip_runtime.h>
#include <hip/hip_bf16.h>

// Problem constants: B=2, T=2048, D=1024, H=16, DK=64
// Math reduction: y = permute(x @ Wv) @ Wo^T  (softmax rowsum == 1 exactly;
// reference's einsum 'bhtl,bthd->bhtd' never contracts v with A over l, so
// o[b,h,t,:] = (sum_l A[b,h,t,l]) * v[b,t,h,:] = v[b,t,h,:]).
// Permute: V[b*2048+t][h*64+k] -> Vp[b*2048 + h*128 + t/16][(t%16)*64 + k]
// Inputs/outputs FP32 (reference dtype); internal bf16 MFMA, fp32 accum.
// R3: double-buffered LDS, prefetch distance 1 — the __syncthreads vmcnt(0)
// drain now waits on a DMA that has had a full iteration in flight, instead
// of stalling every iter on raw load latency (R2's measured bottleneck).

using bf16 = __hip_bfloat16;
typedef __attribute__((ext_vector_type(8))) short bf16x8;   // 8 bf16 = 4 VGPRs
typedef __attribute__((ext_vector_type(4))) float f32x4;

__device__ __forceinline__ void gld_lds16(const void* g, void* l) {
    // async global->LDS, 16B/lane; LDS dest = wave-uniform base + lane*16
    __builtin_amdgcn_global_load_lds(
        (const __attribute__((address_space(1))) void*)g,
        (__attribute__((address_space(3))) void*)l, 16, 0, 0);
}

// ---- fused prep: Wv transpose+cvt | x cvt | Wo cvt, one dispatch ----------
__global__ __launch_bounds__(256) void prep(const float* __restrict__ x,
                                            const float* __restrict__ Wv,
                                            const float* __restrict__ Wo,
                                            bf16* __restrict__ xb,
                                            bf16* __restrict__ WvT,
                                            bf16* __restrict__ Wob) {
    __shared__ float tile[64][65];
    const int id = blockIdx.x;
    const int t  = threadIdx.x;
    if (id < 256) {                       // Wv transpose+convert (64x64 tile)
        const int bx = id & 15, by = id >> 4;
        const int c = t & 63, r4 = t >> 6;
#pragma unroll
        for (int p = 0; p < 16; ++p) {
            int r = p * 4 + r4;
            tile[r][c] = Wv[(size_t)(by * 64 + r) * 1024 + bx * 64 + c];
        }
        __syncthreads();
#pragma unroll
        for (int p = 0; p < 16; ++p) {
            int r = p * 4 + r4;
            WvT[(size_t)(bx * 64 + r) * 1024 + by * 64 + c] = __float2bfloat16(tile[c][r]);
        }
    } else if (id < 4352) {               // x -> bf16, float4 per thread
        const int i = (id - 256) * 256 + t;
        const float4 v = ((const float4*)x)[i];
        bf16 o[4] = {__float2bfloat16(v.x), __float2bfloat16(v.y),
                     __float2bfloat16(v.z), __float2bfloat16(v.w)};
        ((ulong1*)xb)[i] = *(ulong1*)o;
    } else {                              // Wo -> bf16
        const int i = (id - 4352) * 256 + t;
        const float4 v = ((const float4*)Wo)[i];
        bf16 o[4] = {__float2bfloat16(v.x), __float2bfloat16(v.y),
                     __float2bfloat16(v.z), __float2bfloat16(v.w)};
        ((ulong1*)Wob)[i] = *(ulong1*)o;
    }
}

// ---------------- GEMM  C = A(Mx1024) * Bt(Nx1024)^T -----------------------
// A, Bt bf16 row-major [.][K]: both operands K-contiguous.
// 128x64 tile / 256 threads; 4 waves in 2x2, each wave 64x32 = 4x2 accs.
// Double-buffered LDS: buf = 6144 elems (A 128x32 @ [0:4096], B 64x32 @
// [4096:6144]); one __syncthreads per iter; DMA for iter i+1 issued at top
// of iter i, drained by the barrier at iter i+1 (full iteration in flight).
__device__ __forceinline__ void storeC(float v, bf16* p)  { *p = __float2bfloat16(v); }
__device__ __forceinline__ void storeC(float v, float* p) { *p = v; }

template <bool PERMUTE, typename OutT>
__global__ __launch_bounds__(256) void gemm_bt(const bf16* __restrict__ A,
                                               const bf16* __restrict__ Bt,
                                               OutT* __restrict__ C) {
    __shared__ __align__(16) bf16 st[2][6144];    // 2 x 12 KB

    const int tid  = threadIdx.x;
    const int wave = tid >> 6;
    const int lane = tid & 63;
    const int m0 = blockIdx.x * 128;
    const int n0 = blockIdx.y * 64;

    // wave -> 64x32 quadrant of the 128x64 tile
    const int wr = (wave >> 1) * 64;
    const int wc = (wave & 1) * 32;

    // staging: thread t covers row tid>>2 (0..63), col (tid&3)*8;
    // LDS elem offset = row*32+col = tid*8 (matches lane*16B DMA order)
    const int srow = tid >> 2;
    const int scol = (tid & 3) * 8;
    const bf16* gA = A  + (size_t)(m0 + srow) * 1024 + scol;
    const bf16* gB = Bt + (size_t)(n0 + srow) * 1024 + scol;
    const int woff = wave * 512;          // elems, wave-uniform LDS base

    f32x4 acc[4][2];
#pragma unroll
    for (int i = 0; i < 4; ++i)
#pragma unroll
        for (int j = 0; j < 2; ++j)
            acc[i][j] = (f32x4){0.f, 0.f, 0.f, 0.f};

    const int fr = lane & 15;             // fragment row (A) / col (B)
    const int q8 = (lane >> 4) * 8;       // k offset within BK=32

    // prefetch iter 0 into buf 0
    {
        bf16* s = st[0];
        gld_lds16(gA,             s + woff);
        gld_lds16(gA + 64 * 1024, s + 2048 + woff);
        gld_lds16(gB,             s + 4096 + woff);
    }

    for (int i = 0; i < 32; ++i) {
        __syncthreads();                  // drains vmcnt -> buf i&1 visible;
                                          // also: all waves done reading buf (i+1)&1
        if (i < 31) {                     // prefetch iter i+1 into other buf
            const int kt = (i + 1) * 32;
            bf16* s = st[(i + 1) & 1];
            gld_lds16(gA + kt,             s + woff);
            gld_lds16(gA + kt + 64 * 1024, s + 2048 + woff);
            gld_lds16(gB + kt,             s + 4096 + woff);
        }

        const bf16* sAb = st[i & 1];
        const bf16* sBb = st[i & 1] + 4096;
        bf16x8 aF[4], bF[2];
#pragma unroll
        for (int ii = 0; ii < 4; ++ii)
            aF[ii] = *(const bf16x8*)&sAb[(wr + ii * 16 + fr) * 32 + q8];
#pragma unroll
        for (int j = 0; j < 2; ++j)
            bF[j] = *(const bf16x8*)&sBb[(wc + j * 16 + fr) * 32 + q8];
#pragma unroll
        for (int ii = 0; ii < 4; ++ii)
#pragma unroll
            for (int j = 0; j < 2; ++j)
                acc[ii][j] = __builtin_amdgcn_mfma_f32_16x16x32_bf16(
                    aF[ii], bF[j], acc[ii][j], 0, 0, 0);
    }

    // epilogue: C/D layout col=lane&15, row=(lane>>4)*4+reg  [m91-verified]
#pragma unroll
    for (int i = 0; i < 4; ++i) {
#pragma unroll
        for (int j = 0; j < 2; ++j) {
            const int col = n0 + wc + j * 16 + (lane & 15);
#pragma unroll
            for (int r = 0; r < 4; ++r) {
                const int row = m0 + wr + i * 16 + (lane >> 4) * 4 + r;
                if (PERMUTE) {
                    const int b = row >> 11, t = row & 2047;
                    const int h = col >> 6,  k = col & 63;
                    const int rr = (b << 11) | (h << 7) | (t >> 4);
                    const int cc = ((t & 15) << 6) | k;
                    storeC(acc[i][j][r], &C[(size_t)rr * 1024 + cc]);
                } else {
                    storeC(acc[i][j][r], &C[(size_t)row * 1024 + col]);
                }
            }
        }
    }
}

extern "C" void kernel_launch(void* const* d_in, const int* in_sizes, int n_in,
                              void* d_out, int out_size, void* d_ws, size_t ws_size,
                              hipStream_t stream) {
    (void)in_sizes; (void)n_in; (void)out_size; (void)ws_size;
    // inputs (fp32): x, mask, Wq, Wk, Wv, Wo  (mask/Wq/Wk dead — see header)
    const float* x  = (const float*)d_in[0];
    const float* Wv = (const float*)d_in[4];
    const float* Wo = (const float*)d_in[5];
    float* out = (float*)d_out;

    bf16* xb    = (bf16*)d_ws;                 // 4096*1024 bf16 = 8 MB
    bf16* WvT   = xb    + 4096 * 1024;         // 2 MB
    bf16* Wob   = WvT   + 1024 * 1024;         // 2 MB
    bf16* vperm = Wob   + 1024 * 1024;         // 8 MB   (total 20 MB)

    prep<<<5376, 256, 0, stream>>>(x, Wv, Wo, xb, WvT, Wob);
    // V = x @ Wv, written permuted (bf16)
    gemm_bt<true,  bf16 ><<<dim3(32, 16), 256, 0, stream>>>(xb, WvT, vperm);
    // y = Vp @ Wo^T  (fp32 output)
    gemm_bt<false, float><<<dim3(32, 16), 256, 0, stream>>>(vperm, Wob, out);
}

// Round 5
// 115.711 us; speedup vs baseline: 1.1524x; 1.0188x over previous
//
#include <hip/hip_runtime.h>
#include <hip/hip_bf16.h>

// Problem constants: B=2, T=2048, D=1024, H=16, DK=64
// Math reduction: y = permute(x @ Wv) @ Wo^T  (softmax rowsum == 1 exactly;
// reference's einsum 'bhtl,bthd->bhtd' never contracts v with A over l, so
// o[b,h,t,:] = (sum_l A[b,h,t,l]) * v[b,t,h,:] = v[b,t,h,:]).
// Permute: V[b*2048+t][h*64+k] -> Vp[b*2048 + h*128 + t/16][(t%16)*64 + k]
// Inputs/outputs FP32 (reference dtype); internal bf16 MFMA, fp32 accum.
// R4: XOR-swizzled LDS chunk slots. Old layout row*64B made fragment
// ds_read_b128 8-way bank-conflicted (row stride = 16 banks -> fr lanes
// alternate between 2 bank quads, 8 lanes/quad ~ 2.94x serialization).
// Chunk g of row r now lives at slot g^((r>>1)&3): per-16-lane phase the
// reads spread over 8 quads, 2 lanes each -> conflict-free (m136: 2-way
// is free). Swizzle applied on the DMA's *global* side (per-lane source
// address), so global coalescing and the wave-uniform LDS dest both hold.

using bf16 = __hip_bfloat16;
typedef __attribute__((ext_vector_type(8))) short bf16x8;   // 8 bf16 = 4 VGPRs
typedef __attribute__((ext_vector_type(4))) float f32x4;

__device__ __forceinline__ void gld_lds16(const void* g, void* l) {
    // async global->LDS, 16B/lane; LDS dest = wave-uniform base + lane*16
    __builtin_amdgcn_global_load_lds(
        (const __attribute__((address_space(1))) void*)g,
        (__attribute__((address_space(3))) void*)l, 16, 0, 0);
}

// ---- fused prep: Wv transpose+cvt | x cvt | Wo cvt, one dispatch ----------
__global__ __launch_bounds__(256) void prep(const float* __restrict__ x,
                                            const float* __restrict__ Wv,
                                            const float* __restrict__ Wo,
                                            bf16* __restrict__ xb,
                                            bf16* __restrict__ WvT,
                                            bf16* __restrict__ Wob) {
    __shared__ float tile[64][65];
    const int id = blockIdx.x;
    const int t  = threadIdx.x;
    if (id < 256) {                       // Wv transpose+convert (64x64 tile)
        const int bx = id & 15, by = id >> 4;
        const int c = t & 63, r4 = t >> 6;
#pragma unroll
        for (int p = 0; p < 16; ++p) {
            int r = p * 4 + r4;
            tile[r][c] = Wv[(size_t)(by * 64 + r) * 1024 + bx * 64 + c];
        }
        __syncthreads();
#pragma unroll
        for (int p = 0; p < 16; ++p) {
            int r = p * 4 + r4;
            WvT[(size_t)(bx * 64 + r) * 1024 + by * 64 + c] = __float2bfloat16(tile[c][r]);
        }
    } else if (id < 4352) {               // x -> bf16, float4 per thread
        const int i = (id - 256) * 256 + t;
        const float4 v = ((const float4*)x)[i];
        bf16 o[4] = {__float2bfloat16(v.x), __float2bfloat16(v.y),
                     __float2bfloat16(v.z), __float2bfloat16(v.w)};
        ((ulong1*)xb)[i] = *(ulong1*)o;
    } else {                              // Wo -> bf16
        const int i = (id - 4352) * 256 + t;
        const float4 v = ((const float4*)Wo)[i];
        bf16 o[4] = {__float2bfloat16(v.x), __float2bfloat16(v.y),
                     __float2bfloat16(v.z), __float2bfloat16(v.w)};
        ((ulong1*)Wob)[i] = *(ulong1*)o;
    }
}

// ---------------- GEMM  C = A(Mx1024) * Bt(Nx1024)^T -----------------------
// A, Bt bf16 row-major [.][K]: both operands K-contiguous.
// 128x64 tile / 256 threads; 4 waves in 2x2, each wave 64x32 = 4x2 accs.
// Double-buffered LDS + distance-1 DMA prefetch; XOR-swizzled chunk slots.
__device__ __forceinline__ void storeC(float v, bf16* p)  { *p = __float2bfloat16(v); }
__device__ __forceinline__ void storeC(float v, float* p) { *p = v; }

template <bool PERMUTE, typename OutT>
__global__ __launch_bounds__(256) void gemm_bt(const bf16* __restrict__ A,
                                               const bf16* __restrict__ Bt,
                                               OutT* __restrict__ C) {
    __shared__ __align__(16) bf16 st[2][6144];    // 2 x 12 KB

    const int tid  = threadIdx.x;
    const int wave = tid >> 6;
    const int lane = tid & 63;
    const int m0 = blockIdx.x * 128;
    const int n0 = blockIdx.y * 64;

    // wave -> 64x32 quadrant of the 128x64 tile
    const int wr = (wave >> 1) * 64;
    const int wc = (wave & 1) * 32;

    // staging: thread t covers tile row tid>>2, 16B chunk slot tid&3.
    // Swizzle: slot s of row r holds global chunk g = s ^ ((r>>1)&3).
    const int srow = tid >> 2;
    const int scol = (((tid & 3) ^ ((tid >> 3) & 3)) & 3) * 8;  // global k-offset (elems)
    const bf16* gA = A  + (size_t)(m0 + srow) * 1024 + scol;
    const bf16* gB = Bt + (size_t)(n0 + srow) * 1024 + scol;
    const int woff = wave * 512;          // elems, wave-uniform LDS base

    f32x4 acc[4][2];
#pragma unroll
    for (int i = 0; i < 4; ++i)
#pragma unroll
        for (int j = 0; j < 2; ++j)
            acc[i][j] = (f32x4){0.f, 0.f, 0.f, 0.f};

    const int fr = lane & 15;             // fragment row (A) / col (B)
    // fragment wants global chunk g = lane>>4 of row (..+fr); that chunk
    // sits at swizzled slot (lane>>4) ^ ((row>>1)&3) = (lane>>4) ^ ((fr>>1)&3)
    // (wr/wc/ii*16/j*16 all vanish mod 4 after >>1) — loop-invariant:
    const int q8 = ((((lane >> 4) ^ (lane >> 1)) & 3)) * 8;

    // prefetch iter 0 into buf 0
    {
        bf16* s = st[0];
        gld_lds16(gA,             s + woff);
        gld_lds16(gA + 64 * 1024, s + 2048 + woff);
        gld_lds16(gB,             s + 4096 + woff);
    }

    for (int i = 0; i < 32; ++i) {
        __syncthreads();                  // drains vmcnt -> buf i&1 visible;
                                          // also: all waves done reading buf (i+1)&1
        if (i < 31) {                     // prefetch iter i+1 into other buf
            const int kt = (i + 1) * 32;
            bf16* s = st[(i + 1) & 1];
            gld_lds16(gA + kt,             s + woff);
            gld_lds16(gA + kt + 64 * 1024, s + 2048 + woff);
            gld_lds16(gB + kt,             s + 4096 + woff);
        }

        const bf16* sAb = st[i & 1];
        const bf16* sBb = st[i & 1] + 4096;
        bf16x8 aF[4], bF[2];
#pragma unroll
        for (int ii = 0; ii < 4; ++ii)
            aF[ii] = *(const bf16x8*)&sAb[(wr + ii * 16 + fr) * 32 + q8];
#pragma unroll
        for (int j = 0; j < 2; ++j)
            bF[j] = *(const bf16x8*)&sBb[(wc + j * 16 + fr) * 32 + q8];
#pragma unroll
        for (int ii = 0; ii < 4; ++ii)
#pragma unroll
            for (int j = 0; j < 2; ++j)
                acc[ii][j] = __builtin_amdgcn_mfma_f32_16x16x32_bf16(
                    aF[ii], bF[j], acc[ii][j], 0, 0, 0);
    }

    // epilogue: C/D layout col=lane&15, row=(lane>>4)*4+reg  [m91-verified]
#pragma unroll
    for (int i = 0; i < 4; ++i) {
#pragma unroll
        for (int j = 0; j < 2; ++j) {
            const int col = n0 + wc + j * 16 + (lane & 15);
#pragma unroll
            for (int r = 0; r < 4; ++r) {
                const int row = m0 + wr + i * 16 + (lane >> 4) * 4 + r;
                if (PERMUTE) {
                    const int b = row >> 11, t = row & 2047;
                    const int h = col >> 6,  k = col & 63;
                    const int rr = (b << 11) | (h << 7) | (t >> 4);
                    const int cc = ((t & 15) << 6) | k;
                    storeC(acc[i][j][r], &C[(size_t)rr * 1024 + cc]);
                } else {
                    storeC(acc[i][j][r], &C[(size_t)row * 1024 + col]);
                }
            }
        }
    }
}

extern "C" void kernel_launch(void* const* d_in, const int* in_sizes, int n_in,
                              void* d_out, int out_size, void* d_ws, size_t ws_size,
                              hipStream_t stream) {
    (void)in_sizes; (void)n_in; (void)out_size; (void)ws_size;
    // inputs (fp32): x, mask, Wq, Wk, Wv, Wo  (mask/Wq/Wk dead — see header)
    const float* x  = (const float*)d_in[0];
    const float* Wv = (const float*)d_in[4];
    const float* Wo = (const float*)d_in[5];
    float* out = (float*)d_out;

    bf16* xb    = (bf16*)d_ws;                 // 4096*1024 bf16 = 8 MB
    bf16* WvT   = xb    + 4096 * 1024;         // 2 MB
    bf16* Wob   = WvT   + 1024 * 1024;         // 2 MB
    bf16* vperm = Wob   + 1024 * 1024;         // 8 MB   (total 20 MB)

    prep<<<5376, 256, 0, stream>>>(x, Wv, Wo, xb, WvT, Wob);
    // V = x @ Wv, written permuted (bf16)
    gemm_bt<true,  bf16 ><<<dim3(32, 16), 256, 0, stream>>>(xb, WvT, vperm);
    // y = Vp @ Wo^T  (fp32 output)
    gemm_bt<false, float><<<dim3(32, 16), 256, 0, stream>>>(vperm, Wob, out);
}